// Round 1
// 256.928 us; speedup vs baseline: 1.0418x; 1.0418x over previous
//
#include <hip/hip_runtime.h>

// SparseMeanPool: out[b,d,r,c] = adaptive-pool diagonal map of x[b,d,:64].
// B*D = 16384 rows; each row emits a 64x64 fp32 tile (16 KB contiguous).
// Pure write-bound: 256 MiB out vs 4 MiB in. Each cell's pooling window
// [s,e) is a compile-time constant -> 8 KB __constant__ table, unpacked
// into registers once per block and reused across 4 rows.
//
// R1 change: plain stores instead of __builtin_nontemporal_store.
// The 256 MiB output fits the 256 MiB Infinity Cache; nt forced every
// store to HBM rate (~2.8 TB/s observed), while regular stores retire
// into L2/L3 and drain lazily (fill kernel shows >=6.3 TB/s this way).

#define N 64
#define NCELLS (N * N)
#define NROWS (32 * 512)
#define RPB 4                      // rows per block

typedef float fvec4 __attribute__((ext_vector_type(4)));

struct Tab { unsigned short v[NCELLS]; };

constexpr Tab make_tab() {
    Tab t{};
    for (int i = 0; i < NCELLS; ++i) t.v[i] = 0;           // s=e=0 -> zero cell
    // main diagonal: raw x[r] == mean over window [r, r+1)
    for (int d = 0; d < N; ++d)
        t.v[d * N + d] = (unsigned short)(d | ((d + 1) << 8));
    const int counts[3] = {15, 8, 8};
    int stride = 1, offset = 0;
    for (int g = 0; g < 3; ++g) {
        for (int c = 0; c < counts[g]; ++c) {
            offset += stride;
            int L = 0;
            for (int i = 0; i < N - offset; i += stride) ++L;  // diagonal length
            int k = 0;
            for (int i = 0; i < N - offset; i += stride, ++k) {
                int j = offset + k * stride;                    // == i + offset
                int s = (k * N) / L;                            // floor
                int e = ((k + 1) * N + L - 1) / L;              // ceil
                t.v[i * N + j] = (unsigned short)(s | (e << 8));
            }
        }
        stride *= 2;
    }
    return t;
}

struct Recip { float v[N + 1]; };
constexpr Recip make_recip() {
    Recip r{};
    r.v[0] = 0.0f;                       // zero cells: 0 * 0 = 0
    for (int i = 1; i <= N; ++i) r.v[i] = 1.0f / (float)i;
    return r;
}

constexpr Tab   HTAB   = make_tab();
constexpr Recip HRECIP = make_recip();
__constant__ Tab   TAB   = HTAB;
__constant__ Recip RECIP = HRECIP;

__global__ __launch_bounds__(256) void sparse_mean_pool_kernel(
        const float* __restrict__ x, float* __restrict__ out) {
    __shared__ float csum[RPB][N + 1];
    const int t    = threadIdx.x;
    const int wv   = t >> 6;           // wave id 0..3 -> row within block
    const int lane = t & 63;
    const size_t row0 = (size_t)blockIdx.x * RPB;

    // --- each wave builds the prefix sum for its own row (all 256 active) ---
    {
        float v = x[(row0 + wv) * N + lane];
        #pragma unroll
        for (int off = 1; off < N; off <<= 1) {
            float nb = __shfl_up(v, off, 64);
            if (lane >= off) v += nb;
        }
        csum[wv][lane + 1] = v;
        if (lane == 0) csum[wv][0] = 0.0f;
    }

    // --- unpack this thread's 16-cell table slice into registers (once) ---
    int   s_i[16], e_i[16];
    float rc_i[16];
    #pragma unroll
    for (int it = 0; it < 4; ++it) {
        const int f = t + it * 256;    // float4 index in [0,1024)
        const ushort4 p4 = *(const ushort4*)(TAB.v + f * 4);
        const unsigned short ps[4] = {p4.x, p4.y, p4.z, p4.w};
        #pragma unroll
        for (int u = 0; u < 4; ++u) {
            const int k = it * 4 + u;
            s_i[k]  = ps[u] & 0xFF;
            e_i[k]  = ps[u] >> 8;
            rc_i[k] = RECIP.v[e_i[k] - s_i[k]];
        }
    }
    __syncthreads();

    // --- write 4 row-tiles: 16 fvec4 stores/thread, coalesced ---
    #pragma unroll
    for (int r = 0; r < RPB; ++r) {
        const float* cs = csum[r];
        fvec4* orow = (fvec4*)(out + (row0 + r) * (size_t)NCELLS);
        #pragma unroll
        for (int it = 0; it < 4; ++it) {
            const int f = t + it * 256;
            fvec4 v;
            v.x = (cs[e_i[it*4+0]] - cs[s_i[it*4+0]]) * rc_i[it*4+0];
            v.y = (cs[e_i[it*4+1]] - cs[s_i[it*4+1]]) * rc_i[it*4+1];
            v.z = (cs[e_i[it*4+2]] - cs[s_i[it*4+2]]) * rc_i[it*4+2];
            v.w = (cs[e_i[it*4+3]] - cs[s_i[it*4+3]]) * rc_i[it*4+3];
            orow[f] = v;
        }
    }
}

extern "C" void kernel_launch(void* const* d_in, const int* in_sizes, int n_in,
                              void* d_out, int out_size, void* d_ws, size_t ws_size,
                              hipStream_t stream) {
    const float* x = (const float*)d_in[0];
    float* out = (float*)d_out;
    sparse_mean_pool_kernel<<<NROWS / RPB, 256, 0, stream>>>(x, out);
}